// Round 1
// 11196.886 us; speedup vs baseline: 1.1384x; 1.1384x over previous
//
#include <hip/hip_runtime.h>

// RNN scan, MI355X. Round 3: batch-split scan — ZERO inter-WG communication.
// Key insight: the recurrence couples only the H dim; batch rows are independent.
// Phase 0: repack W_hh (ks 8..15) into bf16 MFMA fragments in d_ws (256 KB).
// Phase 1: Xp = X@W_xh + b_h via bf16 MFMA into d_out[0..T) (unchanged).
// Phase 2: 4 WGs x 16 batches. Per wave (128 cols): W^T frags 3-tier resident:
//   ks0..7 in VGPRs (256 regs, once), ks8..11 in LDS (128 KiB, once),
//   ks12..15 streamed from L2 every step (32KB/wave, hidden under MFMA).
//   Swapped-operand MFMA (A=W^T, B=h) makes both hA write (b64) and out store
//   (f32x4) contiguous per lane. h lives in LDS bf16 for all 2048 steps;
//   only sync = 2 __syncthreads()/step. No fences, no flags, no slots.

typedef short bf16x8 __attribute__((ext_vector_type(8)));
typedef short bf16x4 __attribute__((ext_vector_type(4)));
typedef float f32x4 __attribute__((ext_vector_type(4)));

#define T_STEPS 2048
#define BATCH 64
#define HDIM 512
#define EDIM 512
#define BH (BATCH * HDIM)       // 32768 floats per timestep
#define NWG 4                   // batch-split workgroups
#define BPG 16                  // batches per WG (one 16-row MFMA N-tile)
#define HA_PITCH 520            // shorts per hA row: 512 + 8 (16B mult; conflict-free b128 reads)

__device__ __forceinline__ short f2bf(float x) {
  unsigned u = __float_as_uint(x);
  u = (u + 0x7FFFu + ((u >> 16) & 1u)) >> 16;   // round-to-nearest-even
  return (short)u;
}

// tanh(x) = 1 - 2/(e^{2x}+1); v_exp + v_rcp, ~5 instrs. abs err ~2e-5
// (well under the bf16 h-carry quantum ~4e-3). Saturates correctly at +-inf.
__device__ __forceinline__ float fast_tanh(float x) {
  float e = __expf(2.0f * x);
  return 1.0f - 2.0f * __builtin_amdgcn_rcpf(e + 1.0f);
}

// ---------------- Phase 1: Xp = X @ W_xh + b_h  (bf16 MFMA, unchanged) ----------------
__global__ __launch_bounds__(256) void xp_gemm(const float* __restrict__ X,
                                               const float* __restrict__ Wxh,
                                               const float* __restrict__ bh,
                                               float* __restrict__ out) {
  __shared__ short As[64][40];
  __shared__ short Bs[64][40];
  const int bid = blockIdx.x;
  const int xcd = bid & 7;
  const int s   = bid >> 3;
  const int mt  = (xcd << 8) + (s >> 3);
  const int nt  = s & 7;
  const int tid = threadIdx.x;
  const int lane = tid & 63;
  const int wv   = tid >> 6;
  const int mrow = (wv >> 1) * 32;
  const int ncol = (wv & 1) * 32;

  f32x4 acc00 = {0.f,0.f,0.f,0.f};
  f32x4 acc01 = acc00, acc10 = acc00, acc11 = acc00;

  const int ar = tid >> 2, aq = tid & 3;
  const int bk = tid >> 3, bn = (tid & 7) * 8;

  for (int kt = 0; kt < 16; ++kt) {
    const float* asrc = X + (size_t)(mt * 64 + ar) * EDIM + kt * 32 + aq * 8;
    f32x4 a0 = *(const f32x4*)asrc;
    f32x4 a1 = *(const f32x4*)(asrc + 4);
    const float* bsrc = Wxh + (size_t)(kt * 32 + bk) * HDIM + nt * 64 + bn;
    f32x4 w0 = *(const f32x4*)bsrc;
    f32x4 w1 = *(const f32x4*)(bsrc + 4);

    bf16x8 ap;
    ap[0] = f2bf(a0[0]); ap[1] = f2bf(a0[1]); ap[2] = f2bf(a0[2]); ap[3] = f2bf(a0[3]);
    ap[4] = f2bf(a1[0]); ap[5] = f2bf(a1[1]); ap[6] = f2bf(a1[2]); ap[7] = f2bf(a1[3]);
    *(bf16x8*)&As[ar][aq * 8] = ap;
    Bs[bn + 0][bk] = f2bf(w0[0]);
    Bs[bn + 1][bk] = f2bf(w0[1]);
    Bs[bn + 2][bk] = f2bf(w0[2]);
    Bs[bn + 3][bk] = f2bf(w0[3]);
    Bs[bn + 4][bk] = f2bf(w1[0]);
    Bs[bn + 5][bk] = f2bf(w1[1]);
    Bs[bn + 6][bk] = f2bf(w1[2]);
    Bs[bn + 7][bk] = f2bf(w1[3]);
    __syncthreads();

    const int fm = lane & 15, fq = (lane >> 4) * 8;
    bf16x8 fa0 = *(bf16x8*)&As[mrow + fm][fq];
    bf16x8 fa1 = *(bf16x8*)&As[mrow + 16 + fm][fq];
    bf16x8 fb0 = *(bf16x8*)&Bs[ncol + fm][fq];
    bf16x8 fb1 = *(bf16x8*)&Bs[ncol + 16 + fm][fq];
    acc00 = __builtin_amdgcn_mfma_f32_16x16x32_bf16(fa0, fb0, acc00, 0, 0, 0);
    acc01 = __builtin_amdgcn_mfma_f32_16x16x32_bf16(fa0, fb1, acc01, 0, 0, 0);
    acc10 = __builtin_amdgcn_mfma_f32_16x16x32_bf16(fa1, fb0, acc10, 0, 0, 0);
    acc11 = __builtin_amdgcn_mfma_f32_16x16x32_bf16(fa1, fb1, acc11, 0, 0, 0);
    __syncthreads();
  }

  const int c = lane & 15, r4 = (lane >> 4) * 4;
  #pragma unroll
  for (int i = 0; i < 4; ++i) {
    int gm0 = mt * 64 + mrow + r4 + i;
    int gm1 = gm0 + 16;
    int gn0 = nt * 64 + ncol + c;
    int gn1 = gn0 + 16;
    out[(size_t)gm0 * HDIM + gn0] = acc00[i] + bh[gn0];
    out[(size_t)gm0 * HDIM + gn1] = acc01[i] + bh[gn1];
    out[(size_t)gm1 * HDIM + gn0] = acc10[i] + bh[gn0];
    out[(size_t)gm1 * HDIM + gn1] = acc11[i] + bh[gn1];
  }
}

// ---------------- Phase 0: repack W_hh (ks 8..15) into bf16 frags ----------------
// Frag F(w,kk,nt) = (w*8+kk)*8+nt at wsW + F*512 shorts; lane l owns 16B at +l*16B.
// A-frag of W^T: lane holds W[ks*32 + (l>>4)*8 + j][w*128 + nt*16 + (l&15)].
// Requires ws_size >= 256 KB (same budget the previous kernel used).
__global__ __launch_bounds__(64) void w_repack(const float* __restrict__ Whh,
                                               short* __restrict__ wsW) {
  const int blk = blockIdx.x;     // 32 blocks
  const int w   = blk >> 3;       // col group (wave id) 0..3
  const int kk  = blk & 7;        // ks-8, i.e. ks in 8..15
  const int lane = threadIdx.x;
  const int ln = lane & 15;
  const int kq = (lane >> 4) * 8;
  const int ks = kk + 8;
  #pragma unroll
  for (int nt = 0; nt < 8; ++nt) {
    const int col = w * 128 + nt * 16 + ln;
    const float* src = Whh + (size_t)(ks * 32 + kq) * HDIM + col;
    bf16x8 f;
    #pragma unroll
    for (int j = 0; j < 8; ++j) f[j] = f2bf(src[(size_t)j * HDIM]);
    const int F = (w * 8 + kk) * 8 + nt;
    *(bf16x8*)(wsW + (size_t)F * 512 + lane * 8) = f;
  }
}

// ---------------- Phase 2: batch-split MFMA scan, no inter-WG sync ----------------
__global__ __launch_bounds__(256, 1) void rnn_scan3(const float* __restrict__ Whh,
                                                    float* __restrict__ out,
                                                    const short* __restrict__ wsW) {
  __shared__ short WL[4 * 4 * 8 * 512];   // 128 KiB: W frags ks 8..11, [w][kk][nt][lane*8]
  __shared__ short hA[BPG * HA_PITCH];    // 16.25 KiB: h_{t-1} bf16, [batch][k]

  const int tid  = threadIdx.x;
  const int g    = blockIdx.x;            // batch group: rows g*16..g*16+15
  const int w    = tid >> 6;              // wave id = col group (cols w*128..)
  const int lane = tid & 63;
  const int ln   = lane & 15;
  const int kq   = (lane >> 4) * 8;
  const int r0   = (lane >> 4) * 4;

  // ---- one-time: VGPR-resident W^T frags, ks 0..7 (256 VGPRs) ----
  bf16x8 Wr[8][8];
  #pragma unroll
  for (int ks = 0; ks < 8; ++ks) {
    #pragma unroll
    for (int nt = 0; nt < 8; ++nt) {
      const float* src = Whh + (size_t)(ks * 32 + kq) * HDIM + w * 128 + nt * 16 + ln;
      bf16x8 f;
      #pragma unroll
      for (int j = 0; j < 8; ++j) f[j] = f2bf(src[(size_t)j * HDIM]);
      Wr[ks][nt] = f;
    }
  }

  // ---- one-time: LDS-resident W frags ks 8..11 via direct global->LDS ----
  #pragma unroll
  for (int kk = 0; kk < 4; ++kk) {
    #pragma unroll
    for (int nt = 0; nt < 8; ++nt) {
      const short* gp = wsW + (size_t)((w * 8 + kk) * 8 + nt) * 512 + lane * 8;
      __builtin_amdgcn_global_load_lds(
          (const __attribute__((address_space(1))) void*)gp,
          (__attribute__((address_space(3))) void*)&WL[((w * 4 + kk) * 8 + nt) * 512],
          16, 0, 0);
    }
  }

  // zero hA (h_0 = 0)
  for (int i = tid; i < BPG * HA_PITCH; i += 256) hA[i] = 0;
  __syncthreads();   // drains vmcnt -> WL ready

  const size_t xrow = (size_t)(g * BPG + ln) * HDIM + w * 128 + r0;
  const short* hbase = &hA[ln * HA_PITCH + kq];
  const short* sbase = wsW + (size_t)w * 32768 + lane * 8;   // this wave's frag region

  #pragma unroll 1
  for (int t = 0; t < T_STEPS; ++t) {
    // ---- stream issue: sA <- ks12, sB <- ks13 (XCD-L2-resident after step 0) ----
    bf16x8 sA[8], sB[8];
    #pragma unroll
    for (int nt = 0; nt < 8; ++nt)
      sA[nt] = *(const bf16x8*)(sbase + (size_t)(4 * 8 + nt) * 512);
    #pragma unroll
    for (int nt = 0; nt < 8; ++nt)
      sB[nt] = *(const bf16x8*)(sbase + (size_t)(5 * 8 + nt) * 512);

    // ---- Xp prefetch (consumed only at tanh -> HBM latency hidden by MFMA) ----
    f32x4 xp[8];
    const float* xb = out + (size_t)t * BH + xrow;
    #pragma unroll
    for (int nt = 0; nt < 8; ++nt) xp[nt] = *(const f32x4*)(xb + nt * 16);

    f32x4 acc[8];
    #pragma unroll
    for (int nt = 0; nt < 8; ++nt) acc[nt] = (f32x4){0.f, 0.f, 0.f, 0.f};

    // ks 0..3 (register W)
    #pragma unroll
    for (int ks = 0; ks < 4; ++ks) {
      bf16x8 hf = *(const bf16x8*)(hbase + ks * 32);
      #pragma unroll
      for (int nt = 0; nt < 8; ++nt)
        acc[nt] = __builtin_amdgcn_mfma_f32_16x16x32_bf16(Wr[ks][nt], hf, acc[nt], 0, 0, 0);
    }
    // ks 12 (sA), then refill sA <- ks14 (~775 cy of compute before use)
    {
      bf16x8 hf = *(const bf16x8*)(hbase + 12 * 32);
      #pragma unroll
      for (int nt = 0; nt < 8; ++nt)
        acc[nt] = __builtin_amdgcn_mfma_f32_16x16x32_bf16(sA[nt], hf, acc[nt], 0, 0, 0);
    }
    #pragma unroll
    for (int nt = 0; nt < 8; ++nt)
      sA[nt] = *(const bf16x8*)(sbase + (size_t)(6 * 8 + nt) * 512);
    // ks 4..7 (register W)
    #pragma unroll
    for (int ks = 4; ks < 8; ++ks) {
      bf16x8 hf = *(const bf16x8*)(hbase + ks * 32);
      #pragma unroll
      for (int nt = 0; nt < 8; ++nt)
        acc[nt] = __builtin_amdgcn_mfma_f32_16x16x32_bf16(Wr[ks][nt], hf, acc[nt], 0, 0, 0);
    }
    // ks 13 (sB), then refill sB <- ks15
    {
      bf16x8 hf = *(const bf16x8*)(hbase + 13 * 32);
      #pragma unroll
      for (int nt = 0; nt < 8; ++nt)
        acc[nt] = __builtin_amdgcn_mfma_f32_16x16x32_bf16(sB[nt], hf, acc[nt], 0, 0, 0);
    }
    #pragma unroll
    for (int nt = 0; nt < 8; ++nt)
      sB[nt] = *(const bf16x8*)(sbase + (size_t)(7 * 8 + nt) * 512);
    // ks 8..11 (LDS W)
    #pragma unroll
    for (int kk = 0; kk < 4; ++kk) {
      bf16x8 hf = *(const bf16x8*)(hbase + (8 + kk) * 32);
      #pragma unroll
      for (int nt = 0; nt < 8; ++nt) {
        bf16x8 wl = *(const bf16x8*)&WL[((w * 4 + kk) * 8 + nt) * 512 + lane * 8];
        acc[nt] = __builtin_amdgcn_mfma_f32_16x16x32_bf16(wl, hf, acc[nt], 0, 0, 0);
      }
    }
    // ks 14 (sA)
    {
      bf16x8 hf = *(const bf16x8*)(hbase + 14 * 32);
      #pragma unroll
      for (int nt = 0; nt < 8; ++nt)
        acc[nt] = __builtin_amdgcn_mfma_f32_16x16x32_bf16(sA[nt], hf, acc[nt], 0, 0, 0);
    }
    // ks 15 (sB)
    {
      bf16x8 hf = *(const bf16x8*)(hbase + 15 * 32);
      #pragma unroll
      for (int nt = 0; nt < 8; ++nt)
        acc[nt] = __builtin_amdgcn_mfma_f32_16x16x32_bf16(sB[nt], hf, acc[nt], 0, 0, 0);
    }

    // ---- tanh; fp32 out store (no barrier needed: disjoint per wave); pack bf16 ----
    bf16x4 hp[8];
    float* ob = out + (size_t)t * BH + xrow;
    #pragma unroll
    for (int nt = 0; nt < 8; ++nt) {
      f32x4 v;
      #pragma unroll
      for (int i = 0; i < 4; ++i) v[i] = fast_tanh(acc[nt][i] + xp[nt][i]);
      *(f32x4*)(ob + nt * 16) = v;
      if (t == T_STEPS - 1)   // h_last tail output
        *(f32x4*)(out + (size_t)T_STEPS * BH + xrow + nt * 16) = v;
      bf16x4 p;
      p[0] = f2bf(v[0]); p[1] = f2bf(v[1]); p[2] = f2bf(v[2]); p[3] = f2bf(v[3]);
      hp[nt] = p;
    }

    __syncthreads();   // all waves done READING hA(t-1)
    #pragma unroll
    for (int nt = 0; nt < 8; ++nt)
      *(bf16x4*)&hA[ln * HA_PITCH + w * 128 + nt * 16 + r0] = hp[nt];
    __syncthreads();   // h_t visible to all waves
  }
}

extern "C" void kernel_launch(void* const* d_in, const int* in_sizes, int n_in,
                              void* d_out, int out_size, void* d_ws, size_t ws_size,
                              hipStream_t stream) {
  const float* X   = (const float*)d_in[0];
  const float* Wxh = (const float*)d_in[1];
  const float* Whh = (const float*)d_in[2];
  const float* bh  = (const float*)d_in[3];
  float* out = (float*)d_out;
  short* wsW = (short*)d_ws;   // 256 KB packed W frags (ks 8..15)

  w_repack<<<dim3(32), dim3(64), 0, stream>>>(Whh, wsW);
  xp_gemm<<<dim3(16384), dim3(256), 0, stream>>>(X, Wxh, bh, out);
  rnn_scan3<<<dim3(NWG), dim3(256), 0, stream>>>(Whh, out, wsW);
}